// Round 6
// baseline (3344.261 us; speedup 1.0000x reference)
//
#include <hip/hip_runtime.h>
#include <math.h>

// ---------------------------------------------------------------------------
// Heterogeneous GraphSAGE (3 types, 6 relations, D=128, L=3) + MLP head.
// Round 5: (a) fuse segment-mean agg into the sage MFMA kernel via an LDS
// msg tile (kills the 1.7 GB msg round-trip); (b) head = LN kernel + generic
// MFMA GEMM (proven sage machinery, A from global) instead of fp32 head.
// 6-term split-bf16 throughout (verified at the bf16-compare floor).
//
// Node row layout: [performance 0..200000) [artist ..230000) [song ..280000)
// ---------------------------------------------------------------------------

#define NPF 200000
#define NAR 30000
#define NSO 50000

typedef __attribute__((ext_vector_type(8))) short bf16x8;
typedef __attribute__((ext_vector_type(4))) float f32x4;

__device__ __forceinline__ unsigned short f2bf(float f) {
  union { float f; unsigned u; } v; v.f = f;
  unsigned u = v.u;
  u += 0x7FFFu + ((u >> 16) & 1u);
  return (unsigned short)(u >> 16);
}
__device__ __forceinline__ float bf2f(unsigned short h) {
  union { unsigned u; float f; } v; v.u = ((unsigned)h) << 16;
  return v.f;
}

struct BF3 { short h, m, l; };
__device__ __forceinline__ BF3 split3(float f) {
  BF3 r;
  unsigned short hh = f2bf(f);
  float r1 = f - bf2f(hh);
  unsigned short mm = f2bf(r1);
  float r2 = r1 - bf2f(mm);
  r.h = (short)hh; r.m = (short)mm; r.l = (short)f2bf(r2);
  return r;
}

// ---------- gather x0 = emb[nid] ----------
__global__ void k_gather(const int* __restrict__ nid, const float4* __restrict__ emb,
                         float4* __restrict__ dst, int nrow) {
  int i = blockIdx.x * blockDim.x + threadIdx.x;
  if (i >= nrow * 32) return;
  int r = i >> 5, c = i & 31;
  dst[(size_t)r * 32 + c] = emb[(size_t)nid[r] * 32 + c];
}

// ---------- CSR build ----------
__global__ void k_count(const int* __restrict__ dstv, int E, int* __restrict__ cnt) {
  int i = blockIdx.x * blockDim.x + threadIdx.x;
  if (i < E) atomicAdd(&cnt[dstv[i]], 1);
}

__global__ void k_scan_block(const int* __restrict__ cnt, int n, int* __restrict__ part) {
  __shared__ int sd[256];
  int t = threadIdx.x;
  int base = blockIdx.x * 1024 + t * 4;
  int s = 0;
#pragma unroll
  for (int i = 0; i < 4; ++i) { int idx = base + i; if (idx < n) s += cnt[idx]; }
  sd[t] = s; __syncthreads();
  for (int off = 128; off > 0; off >>= 1) { if (t < off) sd[t] += sd[t + off]; __syncthreads(); }
  if (t == 0) part[blockIdx.x] = sd[0];
}

__global__ void k_scan_top(int* part, int nb) {
  __shared__ int sd[256];
  int t = threadIdx.x;
  int v = (t < nb) ? part[t] : 0;
  sd[t] = v; __syncthreads();
  for (int off = 1; off < 256; off <<= 1) {
    int add = (t >= off) ? sd[t - off] : 0;
    __syncthreads();
    sd[t] += add;
    __syncthreads();
  }
  if (t < nb) part[t] = sd[t] - v;  // exclusive
}

__global__ void k_scan_final(const int* __restrict__ cnt, int n, const int* __restrict__ part,
                             int* __restrict__ rp, int E) {
  __shared__ int sd[256];
  int t = threadIdx.x;
  int base = blockIdx.x * 1024 + t * 4;
  int v[4]; int s = 0;
#pragma unroll
  for (int i = 0; i < 4; ++i) { int idx = base + i; v[i] = (idx < n) ? cnt[idx] : 0; s += v[i]; }
  sd[t] = s; __syncthreads();
  for (int off = 1; off < 256; off <<= 1) {
    int add = (t >= off) ? sd[t - off] : 0;
    __syncthreads();
    sd[t] += add;
    __syncthreads();
  }
  int run = part[blockIdx.x] + sd[t] - s;
#pragma unroll
  for (int i = 0; i < 4; ++i) { int idx = base + i; if (idx < n) rp[idx] = run; run += v[i]; }
  if (blockIdx.x == 0 && t == 0) rp[n] = E;
}

__global__ void k_fill(const int* __restrict__ srcv, const int* __restrict__ dstv, int E,
                       const int* __restrict__ rp, int* __restrict__ cur, int* __restrict__ col) {
  int i = blockIdx.x * blockDim.x + threadIdx.x;
  if (i < E) {
    int d = dstv[i];
    int p = atomicAdd(&cur[d], 1);
    col[rp[d] + p] = srcv[i];
  }
}

// ---------- pack weights into MFMA B-fragment order, bf16 hi/mid/lo ----------
// matrix m: [0,18)=Wl[layer*6+r], [18,36)=Wr, [36,39)=pw1[type], [39,42)=pw2[type]
// per-matrix block (49152 ushorts): hi[16384], mid[16384], lo[16384].
// hi index: ((s*8 + t)*64 + lane)*8 + j  ->  W[s*32 + (lane>>4)*8 + j][t*16 + (lane&15)]
#define PKSTRIDE 49152
__global__ void k_packW(const float* __restrict__ Wl, const float* __restrict__ Wr,
                        const float* __restrict__ pw1, const float* __restrict__ pw2,
                        unsigned short* __restrict__ pk) {
  int gid = blockIdx.x * blockDim.x + threadIdx.x;
  if (gid >= 42 * 4 * 8 * 64) return;
  int lane = gid & 63;
  int t = (gid >> 6) & 7;
  int s = (gid >> 9) & 3;
  int m = gid >> 11;
  const float* src;
  if (m < 18) src = Wl + (size_t)m * 16384;
  else if (m < 36) src = Wr + (size_t)(m - 18) * 16384;
  else if (m < 39) src = pw1 + (size_t)(m - 36) * 16384;
  else src = pw2 + (size_t)(m - 39) * 16384;
  int n = t * 16 + (lane & 15);
  int k0 = s * 32 + (lane >> 4) * 8;
  unsigned short* hi = pk + (size_t)m * PKSTRIDE + ((size_t)(s * 8 + t) * 64 + lane) * 8;
  unsigned short* mid = hi + 16384;
  unsigned short* lo = hi + 32768;
#pragma unroll
  for (int j = 0; j < 8; ++j) {
    float f = src[(size_t)(k0 + j) * 128 + n];
    BF3 w = split3(f);
    hi[j] = (unsigned short)w.h;
    mid[j] = (unsigned short)w.m;
    lo[j] = (unsigned short)w.l;
  }
}

// 6-product split-bf16 MFMA accumulate (drops only O(2^-24) terms)
#define MFMA6(ah, am, al, bh, bm, blo, acc)                                     \
  acc = __builtin_amdgcn_mfma_f32_16x16x32_bf16(ah, bh, acc, 0, 0, 0);          \
  acc = __builtin_amdgcn_mfma_f32_16x16x32_bf16(am, bh, acc, 0, 0, 0);          \
  acc = __builtin_amdgcn_mfma_f32_16x16x32_bf16(ah, bm, acc, 0, 0, 0);          \
  acc = __builtin_amdgcn_mfma_f32_16x16x32_bf16(al, bh, acc, 0, 0, 0);          \
  acc = __builtin_amdgcn_mfma_f32_16x16x32_bf16(am, bm, acc, 0, 0, 0);          \
  acc = __builtin_amdgcn_mfma_f32_16x16x32_bf16(ah, blo, acc, 0, 0, 0);

// ---------- fused agg + SAGE: out = l2norm(mean(x_src)@Wl + bl + x_dst@Wr) ----------
// Block = 64 dst rows, 256 thr = 4 waves. Phase A: each wave aggregates its 16
// rows' neighbor means into LDS (wave-per-row, lane = 2 columns — mirrors the
// proven k_agg). Phase B: proven sage MFMA loop, msg-A-fragments from LDS.
__global__ __launch_bounds__(256) void k_sage_fused(
    const int* __restrict__ rp, const int* __restrict__ col,
    const float* __restrict__ xsrc, const float* __restrict__ xdst,
    const unsigned short* __restrict__ pkl, const unsigned short* __restrict__ pkr,
    const float* __restrict__ blv, float* __restrict__ outp,
    int n_dst, int first, int relu_out) {
  __shared__ float Ms[64][132];
  int lane = threadIdx.x & 63;
  int wave = threadIdx.x >> 6;
  int row0b = blockIdx.x * 64;

  // phase A: segment mean into Ms
  for (int i = 0; i < 16; ++i) {
    int lr = wave * 16 + i;
    int d = row0b + lr;
    float ax = 0.f, ay = 0.f;
    if (d < n_dst) {
      int b = rp[d], e = rp[d + 1];
      for (int j = b; j < e; ++j) {
        int s = col[j];
        float2 v = *((const float2*)(xsrc + (size_t)s * 128) + lane);
        ax += v.x; ay += v.y;
      }
      float inv = (e > b) ? 1.0f / (float)(e - b) : 0.0f;
      ax *= inv; ay *= inv;
    }
    *(float2*)&Ms[lr][lane * 2] = make_float2(ax, ay);
  }
  __syncthreads();

  // phase B: sage MFMA (identical to proven k_sage_mfma, msg from LDS)
  int row0 = row0b + wave * 16;
  int cg = lane & 15, qg = lane >> 4;
  int ar = min(row0 + cg, n_dst - 1);
  int lar = wave * 16 + cg;
  int kb = qg * 8;

  f32x4 acc[8];
#pragma unroll
  for (int t = 0; t < 8; ++t) acc[t] = (f32x4){0.f, 0.f, 0.f, 0.f};

#pragma unroll
  for (int sm = 0; sm < 2; ++sm) {
    const unsigned short* pk = sm ? pkr : pkl;
#pragma unroll
    for (int s = 0; s < 4; ++s) {
      const float* ap = sm ? (xdst + (size_t)ar * 128 + s * 32 + kb)
                           : (&Ms[lar][s * 32 + kb]);
      float4 f0 = *(const float4*)ap;
      float4 f1 = *(const float4*)(ap + 4);
      float fa[8] = {f0.x, f0.y, f0.z, f0.w, f1.x, f1.y, f1.z, f1.w};
      bf16x8 ah, am, al;
#pragma unroll
      for (int j = 0; j < 8; ++j) {
        BF3 w = split3(fa[j]);
        ah[j] = w.h; am[j] = w.m; al[j] = w.l;
      }
      const unsigned short* pb = pk + (size_t)s * 4096 + (size_t)lane * 8;
#pragma unroll
      for (int t = 0; t < 8; ++t) {
        bf16x8 bh  = *(const bf16x8*)(pb + (size_t)t * 512);
        bf16x8 bm  = *(const bf16x8*)(pb + (size_t)t * 512 + 16384);
        bf16x8 blo = *(const bf16x8*)(pb + (size_t)t * 512 + 32768);
        MFMA6(ah, am, al, bh, bm, blo, acc[t]);
      }
    }
  }

  // bias
#pragma unroll
  for (int t = 0; t < 8; ++t) {
    float bv = blv[t * 16 + cg];
#pragma unroll
    for (int j = 0; j < 4; ++j) acc[t][j] += bv;
  }
  // l2norm + store/accumulate
  float ss[4];
#pragma unroll
  for (int j = 0; j < 4; ++j) {
    float s = 0.f;
#pragma unroll
    for (int t = 0; t < 8; ++t) s += acc[t][j] * acc[t][j];
    s += __shfl_xor(s, 1); s += __shfl_xor(s, 2);
    s += __shfl_xor(s, 4); s += __shfl_xor(s, 8);
    ss[j] = 1.0f / fmaxf(sqrtf(s), 1e-12f);
  }
#pragma unroll
  for (int j = 0; j < 4; ++j) {
    int r = row0 + qg * 4 + j;
    if (r < n_dst) {
      float* p = outp + (size_t)r * 128 + cg;
      if (first) {
#pragma unroll
        for (int t = 0; t < 8; ++t) p[t * 16] = acc[t][j] * ss[j];
      } else {
#pragma unroll
        for (int t = 0; t < 8; ++t) {
          float v = p[t * 16] + acc[t][j] * ss[j];
          if (relu_out) v = fmaxf(v, 0.f);
          p[t * 16] = v;
        }
      }
    }
  }
}

// ---------- LayerNorm: out[r] = (x-mu)*rsqrt(var+eps)*g + b ----------
__global__ __launch_bounds__(256) void k_ln(const float* __restrict__ in,
                                            float* __restrict__ out, int n,
                                            const float* __restrict__ lng,
                                            const float* __restrict__ lnb) {
  int gid = blockIdx.x * blockDim.x + threadIdx.x;
  int r = gid >> 2, q = gid & 3;
  if (r >= n) return;
  float v[32];
#pragma unroll
  for (int j = 0; j < 8; ++j) {
    float4 t4 = *(const float4*)(in + (size_t)r * 128 + q * 32 + j * 4);
    v[4 * j] = t4.x; v[4 * j + 1] = t4.y; v[4 * j + 2] = t4.z; v[4 * j + 3] = t4.w;
  }
  float s = 0.f, sq = 0.f;
#pragma unroll
  for (int j = 0; j < 32; ++j) { s += v[j]; sq += v[j] * v[j]; }
  s  += __shfl_xor(s, 1);  s  += __shfl_xor(s, 2);
  sq += __shfl_xor(sq, 1); sq += __shfl_xor(sq, 2);
  float mu = s * 0.0078125f;
  float var = sq * 0.0078125f - mu * mu;
  float rs = rsqrtf(var + 1e-5f);
#pragma unroll
  for (int j = 0; j < 8; ++j) {
    float o[4];
#pragma unroll
    for (int k = 0; k < 4; ++k) {
      int c = q * 32 + j * 4 + k;
      o[k] = (v[j * 4 + k] - mu) * rs * lng[c] + lnb[c];
    }
    *(float4*)(out + (size_t)r * 128 + q * 32 + j * 4) = make_float4(o[0], o[1], o[2], o[3]);
  }
}

// ---------- generic MFMA GEMM: out = epi(A@W + bias); epi = relu | l2norm ----------
// Proven sage machinery, single source, A from global rows.
__global__ __launch_bounds__(256) void k_gemm_mfma(
    const float* __restrict__ A, const unsigned short* __restrict__ pk,
    const float* __restrict__ bias, float* __restrict__ outp,
    int n, int relu, int l2n) {
  int lane = threadIdx.x & 63;
  int wave = threadIdx.x >> 6;
  int row0 = blockIdx.x * 64 + wave * 16;
  int cg = lane & 15, qg = lane >> 4;
  int ar = min(row0 + cg, n - 1);
  int kb = qg * 8;

  f32x4 acc[8];
#pragma unroll
  for (int t = 0; t < 8; ++t) acc[t] = (f32x4){0.f, 0.f, 0.f, 0.f};

#pragma unroll
  for (int s = 0; s < 4; ++s) {
    const float* ap = A + (size_t)ar * 128 + s * 32 + kb;
    float4 f0 = *(const float4*)ap;
    float4 f1 = *(const float4*)(ap + 4);
    float fa[8] = {f0.x, f0.y, f0.z, f0.w, f1.x, f1.y, f1.z, f1.w};
    bf16x8 ah, am, al;
#pragma unroll
    for (int j = 0; j < 8; ++j) {
      BF3 w = split3(fa[j]);
      ah[j] = w.h; am[j] = w.m; al[j] = w.l;
    }
    const unsigned short* pb = pk + (size_t)s * 4096 + (size_t)lane * 8;
#pragma unroll
    for (int t = 0; t < 8; ++t) {
      bf16x8 bh  = *(const bf16x8*)(pb + (size_t)t * 512);
      bf16x8 bm  = *(const bf16x8*)(pb + (size_t)t * 512 + 16384);
      bf16x8 blo = *(const bf16x8*)(pb + (size_t)t * 512 + 32768);
      MFMA6(ah, am, al, bh, bm, blo, acc[t]);
    }
  }

#pragma unroll
  for (int t = 0; t < 8; ++t) {
    float bv = bias[t * 16 + cg];
#pragma unroll
    for (int j = 0; j < 4; ++j) acc[t][j] += bv;
  }

  float ss[4];
  if (l2n) {
#pragma unroll
    for (int j = 0; j < 4; ++j) {
      float s = 0.f;
#pragma unroll
      for (int t = 0; t < 8; ++t) s += acc[t][j] * acc[t][j];
      s += __shfl_xor(s, 1); s += __shfl_xor(s, 2);
      s += __shfl_xor(s, 4); s += __shfl_xor(s, 8);
      ss[j] = 1.0f / fmaxf(sqrtf(s), 1e-12f);
    }
  } else {
#pragma unroll
    for (int j = 0; j < 4; ++j) ss[j] = 1.0f;
  }

#pragma unroll
  for (int j = 0; j < 4; ++j) {
    int r = row0 + qg * 4 + j;
    if (r < n) {
      float* p = outp + (size_t)r * 128 + cg;
#pragma unroll
      for (int t = 0; t < 8; ++t) {
        float v = acc[t][j] * ss[j];
        if (relu) v = fmaxf(v, 0.f);
        p[t * 16] = v;
      }
    }
  }
}

// ---------------------------------------------------------------------------
extern "C" void kernel_launch(void* const* d_in, const int* in_sizes, int n_in,
                              void* d_out, int out_size, void* d_ws, size_t ws_size,
                              hipStream_t stream) {
  const int* nid[3] = {(const int*)d_in[0], (const int*)d_in[1], (const int*)d_in[2]};
  const int* eg[6];
  for (int r = 0; r < 6; ++r) eg[r] = (const int*)d_in[3 + r];
  const float* emb[3] = {(const float*)d_in[9], (const float*)d_in[10], (const float*)d_in[11]};
  const float* Wl  = (const float*)d_in[12];
  const float* bl  = (const float*)d_in[13];
  const float* Wr  = (const float*)d_in[14];
  const float* lng = (const float*)d_in[15];
  const float* lnb = (const float*)d_in[16];
  const float* pw1 = (const float*)d_in[17];
  const float* pb1 = (const float*)d_in[18];
  const float* pw2 = (const float*)d_in[19];
  const float* pb2 = (const float*)d_in[20];

  static const int TOFF[3] = {0, NPF, NPF + NAR};
  static const int TN[3]   = {NPF, NAR, NSO};
  struct RelI { int st, dt, E, first; };
  static const RelI R[6] = {
    {1, 0, 400000, 1},   // artist -> performance
    {0, 2, 400000, 1},   // performance -> song
    {1, 2, 150000, 0},   // artist -> song
    {0, 1, 400000, 1},   // performance -> artist
    {2, 0, 400000, 0},   // song -> performance
    {2, 1, 150000, 0},   // song -> artist
  };
  int col_off[6], rp_off[6];
  { int c = 0, p = 0;
    for (int r = 0; r < 6; ++r) { col_off[r] = c; rp_off[r] = p; c += R[r].E; p += TN[R[r].dt] + 1; } }

  // workspace layout (~260.5 MB)
  float* cur = (float*)d_ws;                         // 280000*128 f32 (also head h1 scratch)
  float* msg = cur + (size_t)280000 * 128;           // 200000*128 f32 (head LN scratch)
  int* col   = (int*)(msg + (size_t)200000 * 128);   // 1,900,000
  int* rp    = col + 1900000;                        // 560,006
  int* tmp   = rp + 560006;                          // 200,000
  int* part  = tmp + 200000;                         // 1024
  size_t pk_off = ((size_t)((char*)(part + 1024) - (char*)d_ws) + 255) & ~(size_t)255;
  unsigned short* pkw = (unsigned short*)((char*)d_ws + pk_off);  // 42*49152 ushorts = 4.03 MB
  float* dout = (float*)d_out;

  // pack all weights (42 matrices) into MFMA fragment order, bf16 hi/mid/lo
  k_packW<<<dim3(336), dim3(256), 0, stream>>>(Wl, Wr, pw1, pw2, pkw);

  // x0 = emb[nid]
  for (int t = 0; t < 3; ++t) {
    int tot = TN[t] * 32;
    k_gather<<<dim3((tot + 255) / 256), dim3(256), 0, stream>>>(
        nid[t], (const float4*)emb[t], (float4*)(cur + (size_t)TOFF[t] * 128), TN[t]);
  }

  // CSR per relation
  for (int r = 0; r < 6; ++r) {
    int nd = TN[R[r].dt], E = R[r].E;
    hipMemsetAsync(tmp, 0, (size_t)nd * 4, stream);
    k_count<<<dim3((E + 255) / 256), dim3(256), 0, stream>>>(eg[r] + E, E, tmp);
    int nb = (nd + 1023) / 1024;
    k_scan_block<<<dim3(nb), dim3(256), 0, stream>>>(tmp, nd, part);
    k_scan_top<<<dim3(1), dim3(256), 0, stream>>>(part, nb);
    k_scan_final<<<dim3(nb), dim3(256), 0, stream>>>(tmp, nd, part, rp + rp_off[r], E);
    hipMemsetAsync(tmp, 0, (size_t)nd * 4, stream);
    k_fill<<<dim3((E + 255) / 256), dim3(256), 0, stream>>>(
        eg[r], eg[r] + E, E, rp + rp_off[r], tmp, col + col_off[r]);
  }

  // GNN layers; ping-pong cur <-> d_out (layer0: cur->dout, 1: dout->cur, 2: cur->dout)
  for (int layer = 0; layer < 3; ++layer) {
    float* xin  = (layer == 1) ? dout : cur;
    float* xout = (layer == 1) ? cur  : dout;
    int relu_o = (layer < 2) ? 1 : 0;
    for (int r = 0; r < 6; ++r) {
      int nd = TN[R[r].dt];
      int m = layer * 6 + r;
      const unsigned short* pkl = pkw + (size_t)m * PKSTRIDE;
      const unsigned short* pkr = pkw + (size_t)(18 + m) * PKSTRIDE;
      const float* bb = bl + ((size_t)layer * 6 + r) * 128;
      k_sage_fused<<<dim3((nd + 63) / 64), dim3(256), 0, stream>>>(
          rp + rp_off[r], col + col_off[r],
          xin + (size_t)TOFF[R[r].st] * 128, xin + (size_t)TOFF[R[r].dt] * 128,
          pkl, pkr, bb,
          xout + (size_t)TOFF[R[r].dt] * 128, nd, R[r].first, relu_o);
    }
  }

  // head: per type, LN (dout->msg), GEMM1 relu (msg->cur), GEMM2 l2norm (cur->dout)
  for (int t = 0; t < 3; ++t) {
    int n = TN[t];
    const unsigned short* pk1 = pkw + (size_t)(36 + t) * PKSTRIDE;
    const unsigned short* pk2 = pkw + (size_t)(39 + t) * PKSTRIDE;
    k_ln<<<dim3((n * 4 + 255) / 256), dim3(256), 0, stream>>>(
        dout + (size_t)TOFF[t] * 128, msg, n, lng + t * 128, lnb + t * 128);
    k_gemm_mfma<<<dim3((n + 63) / 64), dim3(256), 0, stream>>>(
        msg, pk1, pb1 + t * 128, cur, n, 1, 0);
    k_gemm_mfma<<<dim3((n + 63) / 64), dim3(256), 0, stream>>>(
        cur, pk2, pb2 + t * 128, dout + (size_t)TOFF[t] * 128, n, 0, 1);
  }

  (void)in_sizes; (void)n_in; (void)out_size; (void)ws_size;
}

// Round 7
// 2094.899 us; speedup vs baseline: 1.5964x; 1.5964x over previous
//
#include <hip/hip_runtime.h>
#include <math.h>

// ---------------------------------------------------------------------------
// Heterogeneous GraphSAGE (3 types, 6 relations, D=128, L=3) + MLP head.
// Round 6: (1) phase-A gather rewritten slot-major w/ 16-lane groups (16x
// memory-level parallelism); (2) sage GEMMs drop to 3-term split-bf16 (head
// stays 6-term); (3) head LN fused into GEMM1; (4) CSR build consolidated
// into one concatenated count/scan/fill.
//
// Node row layout: [performance 0..200000) [artist ..230000) [song ..280000)
// ---------------------------------------------------------------------------

#define NPF 200000
#define NAR 30000
#define NSO 50000
#define NDTOT 560000     // sum of per-relation dst-node counts
#define ETOT  1900000    // total edges
#define VPT 12
#define SCAN_CHUNK (256 * VPT)   // 3072
#define SCAN_NB 183              // ceil(560000/3072)

typedef __attribute__((ext_vector_type(8))) short bf16x8;
typedef __attribute__((ext_vector_type(4))) float f32x4;

__device__ __forceinline__ unsigned short f2bf(float f) {
  union { float f; unsigned u; } v; v.f = f;
  unsigned u = v.u;
  u += 0x7FFFu + ((u >> 16) & 1u);
  return (unsigned short)(u >> 16);
}
__device__ __forceinline__ float bf2f(unsigned short h) {
  union { unsigned u; float f; } v; v.u = ((unsigned)h) << 16;
  return v.f;
}

struct BF3 { short h, m, l; };
__device__ __forceinline__ BF3 split3(float f) {
  BF3 r;
  unsigned short hh = f2bf(f);
  float r1 = f - bf2f(hh);
  unsigned short mm = f2bf(r1);
  float r2 = r1 - bf2f(mm);
  r.h = (short)hh; r.m = (short)mm; r.l = (short)f2bf(r2);
  return r;
}
struct BF2 { short h, m; };
__device__ __forceinline__ BF2 split2(float f) {
  BF2 r;
  unsigned short hh = f2bf(f);
  r.h = (short)hh;
  r.m = (short)f2bf(f - bf2f(hh));
  return r;
}

// 6-product (head) and 3-product (sage) split-bf16 MFMA accumulate
#define MFMA6(ah, am, al, bh, bm, blo, acc)                                     \
  acc = __builtin_amdgcn_mfma_f32_16x16x32_bf16(ah, bh, acc, 0, 0, 0);          \
  acc = __builtin_amdgcn_mfma_f32_16x16x32_bf16(am, bh, acc, 0, 0, 0);          \
  acc = __builtin_amdgcn_mfma_f32_16x16x32_bf16(ah, bm, acc, 0, 0, 0);          \
  acc = __builtin_amdgcn_mfma_f32_16x16x32_bf16(al, bh, acc, 0, 0, 0);          \
  acc = __builtin_amdgcn_mfma_f32_16x16x32_bf16(am, bm, acc, 0, 0, 0);          \
  acc = __builtin_amdgcn_mfma_f32_16x16x32_bf16(ah, blo, acc, 0, 0, 0);
#define MFMA3(ah, am, bh, bm, acc)                                              \
  acc = __builtin_amdgcn_mfma_f32_16x16x32_bf16(ah, bh, acc, 0, 0, 0);          \
  acc = __builtin_amdgcn_mfma_f32_16x16x32_bf16(am, bh, acc, 0, 0, 0);          \
  acc = __builtin_amdgcn_mfma_f32_16x16x32_bf16(ah, bm, acc, 0, 0, 0);

// ---------- fused gather x0 = emb[nid] over all 3 types ----------
__global__ void k_gather_all(const int* __restrict__ nidP, const int* __restrict__ nidA,
                             const int* __restrict__ nidS,
                             const float4* __restrict__ embP, const float4* __restrict__ embA,
                             const float4* __restrict__ embS, float4* __restrict__ dst) {
  int i = blockIdx.x * blockDim.x + threadIdx.x;
  if (i >= 280000 * 32) return;
  int r = i >> 5, c = i & 31;
  const int* nid; const float4* emb; int lr;
  if (r < NPF)            { nid = nidP; emb = embP; lr = r; }
  else if (r < NPF + NAR) { nid = nidA; emb = embA; lr = r - NPF; }
  else                    { nid = nidS; emb = embS; lr = r - NPF - NAR; }
  dst[(size_t)r * 32 + c] = emb[(size_t)nid[lr] * 32 + c];
}

// ---------- concatenated CSR build over all 6 relations ----------
// relation edge ranges: [0,400k) [400k,800k) [800k,950k) [950k,1.35M) [1.35M,1.75M) [1.75M,1.9M)
// cnt offsets (dst nodes): {0, 200000, 250000, 300000, 330000, 530000}
__device__ __forceinline__ void edge_decode(int i,
    const int* e0, const int* e1, const int* e2, const int* e3, const int* e4, const int* e5,
    const int** eg, int* lo, int* E, int* co) {
  if (i < 400000)       { *eg = e0; *lo = i;           *E = 400000; *co = 0; }
  else if (i < 800000)  { *eg = e1; *lo = i - 400000;  *E = 400000; *co = 200000; }
  else if (i < 950000)  { *eg = e2; *lo = i - 800000;  *E = 150000; *co = 250000; }
  else if (i < 1350000) { *eg = e3; *lo = i - 950000;  *E = 400000; *co = 300000; }
  else if (i < 1750000) { *eg = e4; *lo = i - 1350000; *E = 400000; *co = 330000; }
  else                  { *eg = e5; *lo = i - 1750000; *E = 150000; *co = 530000; }
}

__global__ void k_count_all(const int* e0, const int* e1, const int* e2,
                            const int* e3, const int* e4, const int* e5,
                            int* __restrict__ cnt) {
  int i = blockIdx.x * blockDim.x + threadIdx.x;
  if (i >= ETOT) return;
  const int* eg; int lo, E, co;
  edge_decode(i, e0, e1, e2, e3, e4, e5, &eg, &lo, &E, &co);
  atomicAdd(&cnt[co + eg[E + lo]], 1);
}

__global__ void k_scan_block(const int* __restrict__ cnt, int n, int* __restrict__ part) {
  __shared__ int sd[256];
  int t = threadIdx.x;
  int base = blockIdx.x * SCAN_CHUNK + t * VPT;
  int s = 0;
#pragma unroll
  for (int i = 0; i < VPT; ++i) { int idx = base + i; if (idx < n) s += cnt[idx]; }
  sd[t] = s; __syncthreads();
  for (int off = 128; off > 0; off >>= 1) { if (t < off) sd[t] += sd[t + off]; __syncthreads(); }
  if (t == 0) part[blockIdx.x] = sd[0];
}

__global__ void k_scan_top(int* part, int nb) {
  __shared__ int sd[256];
  int t = threadIdx.x;
  int v = (t < nb) ? part[t] : 0;
  sd[t] = v; __syncthreads();
  for (int off = 1; off < 256; off <<= 1) {
    int add = (t >= off) ? sd[t - off] : 0;
    __syncthreads();
    sd[t] += add;
    __syncthreads();
  }
  if (t < nb) part[t] = sd[t] - v;  // exclusive
}

// also zeroes cnt so it can be reused as the fill cursor array
__global__ void k_scan_final(int* __restrict__ cnt, int n, const int* __restrict__ part,
                             int* __restrict__ rp, int E) {
  __shared__ int sd[256];
  int t = threadIdx.x;
  int base = blockIdx.x * SCAN_CHUNK + t * VPT;
  int v[VPT]; int s = 0;
#pragma unroll
  for (int i = 0; i < VPT; ++i) { int idx = base + i; v[i] = (idx < n) ? cnt[idx] : 0; s += v[i]; }
  sd[t] = s; __syncthreads();
  for (int off = 1; off < 256; off <<= 1) {
    int add = (t >= off) ? sd[t - off] : 0;
    __syncthreads();
    sd[t] += add;
    __syncthreads();
  }
  int run = part[blockIdx.x] + sd[t] - s;
#pragma unroll
  for (int i = 0; i < VPT; ++i) {
    int idx = base + i;
    if (idx < n) { rp[idx] = run; cnt[idx] = 0; }
    run += v[i];
  }
  if (blockIdx.x == 0 && t == 0) rp[n] = E;
}

__global__ void k_fill_all(const int* e0, const int* e1, const int* e2,
                           const int* e3, const int* e4, const int* e5,
                           const int* __restrict__ rp, int* __restrict__ cur,
                           int* __restrict__ col) {
  int i = blockIdx.x * blockDim.x + threadIdx.x;
  if (i >= ETOT) return;
  const int* eg; int lo, E, co;
  edge_decode(i, e0, e1, e2, e3, e4, e5, &eg, &lo, &E, &co);
  int d = co + eg[E + lo];
  int p = atomicAdd(&cur[d], 1);
  col[rp[d] + p] = eg[lo];
}

// ---------- pack weights into MFMA B-fragment order, bf16 hi/mid/lo ----------
// matrix m: [0,18)=Wl[layer*6+r], [18,36)=Wr, [36,39)=pw1[type], [39,42)=pw2[type]
#define PKSTRIDE 49152
__global__ void k_packW(const float* __restrict__ Wl, const float* __restrict__ Wr,
                        const float* __restrict__ pw1, const float* __restrict__ pw2,
                        unsigned short* __restrict__ pk) {
  int gid = blockIdx.x * blockDim.x + threadIdx.x;
  if (gid >= 42 * 4 * 8 * 64) return;
  int lane = gid & 63;
  int t = (gid >> 6) & 7;
  int s = (gid >> 9) & 3;
  int m = gid >> 11;
  const float* src;
  if (m < 18) src = Wl + (size_t)m * 16384;
  else if (m < 36) src = Wr + (size_t)(m - 18) * 16384;
  else if (m < 39) src = pw1 + (size_t)(m - 36) * 16384;
  else src = pw2 + (size_t)(m - 39) * 16384;
  int n = t * 16 + (lane & 15);
  int k0 = s * 32 + (lane >> 4) * 8;
  unsigned short* hi = pk + (size_t)m * PKSTRIDE + ((size_t)(s * 8 + t) * 64 + lane) * 8;
  unsigned short* mid = hi + 16384;
  unsigned short* lo = hi + 32768;
#pragma unroll
  for (int j = 0; j < 8; ++j) {
    float f = src[(size_t)(k0 + j) * 128 + n];
    BF3 w = split3(f);
    hi[j] = (unsigned short)w.h;
    mid[j] = (unsigned short)w.m;
    lo[j] = (unsigned short)w.l;
  }
}

// ---------- fused agg + SAGE: out = l2norm(mean(x_src)@Wl + bl + x_dst@Wr) ----------
// Phase A (new): 16-lane groups, 4 rows/group, slot-major neighbor loop ->
// up to 16 rows x 512B gathers in flight per wave. Phase B: 3-term MFMA.
__global__ __launch_bounds__(256) void k_sage_fused(
    const int* __restrict__ rp, const int* __restrict__ col,
    const float* __restrict__ xsrc, const float* __restrict__ xdst,
    const unsigned short* __restrict__ pkl, const unsigned short* __restrict__ pkr,
    const float* __restrict__ blv, float* __restrict__ outp,
    int n_dst, int first, int relu_out) {
  __shared__ float Ms[64][132];
  int lane = threadIdx.x & 63;
  int wave = threadIdx.x >> 6;
  int row0b = blockIdx.x * 64;

  // ---- phase A: segment mean into Ms ----
  {
    int g = lane >> 4, li = lane & 15;
    int c0 = li * 8;
    int bb[4], ne[4];
    int maxd = 0;
#pragma unroll
    for (int i = 0; i < 4; ++i) {
      int d = row0b + wave * 16 + g * 4 + i;
      int b = 0, e = 0;
      if (d < n_dst) { b = rp[d]; e = rp[d + 1]; }
      bb[i] = b; ne[i] = e - b;
      maxd = max(maxd, e - b);
    }
    f32x4 a0[4], a1[4];
#pragma unroll
    for (int i = 0; i < 4; ++i) { a0[i] = (f32x4){0.f,0.f,0.f,0.f}; a1[i] = (f32x4){0.f,0.f,0.f,0.f}; }
    for (int k = 0; k < maxd; ++k) {
#pragma unroll
      for (int i = 0; i < 4; ++i) {
        if (k < ne[i]) {
          int s = col[bb[i] + k];
          const float* sp = xsrc + (size_t)s * 128 + c0;
          float4 v0 = *(const float4*)sp;
          float4 v1 = *(const float4*)(sp + 4);
          a0[i][0] += v0.x; a0[i][1] += v0.y; a0[i][2] += v0.z; a0[i][3] += v0.w;
          a1[i][0] += v1.x; a1[i][1] += v1.y; a1[i][2] += v1.z; a1[i][3] += v1.w;
        }
      }
    }
#pragma unroll
    for (int i = 0; i < 4; ++i) {
      float inv = (ne[i] > 0) ? 1.0f / (float)ne[i] : 0.0f;
      int lr = wave * 16 + g * 4 + i;
      *(float4*)&Ms[lr][c0]     = make_float4(a0[i][0]*inv, a0[i][1]*inv, a0[i][2]*inv, a0[i][3]*inv);
      *(float4*)&Ms[lr][c0 + 4] = make_float4(a1[i][0]*inv, a1[i][1]*inv, a1[i][2]*inv, a1[i][3]*inv);
    }
  }
  __syncthreads();

  // ---- phase B: 3-term split-bf16 MFMA ----
  int row0 = row0b + wave * 16;
  int cg = lane & 15, qg = lane >> 4;
  int ar = min(row0 + cg, n_dst - 1);
  int lar = wave * 16 + cg;
  int kb = qg * 8;

  f32x4 acc[8];
#pragma unroll
  for (int t = 0; t < 8; ++t) acc[t] = (f32x4){0.f, 0.f, 0.f, 0.f};

#pragma unroll
  for (int sm = 0; sm < 2; ++sm) {
    const unsigned short* pk = sm ? pkr : pkl;
#pragma unroll
    for (int s = 0; s < 4; ++s) {
      const float* ap = sm ? (xdst + (size_t)ar * 128 + s * 32 + kb)
                           : (&Ms[lar][s * 32 + kb]);
      float4 f0 = *(const float4*)ap;
      float4 f1 = *(const float4*)(ap + 4);
      float fa[8] = {f0.x, f0.y, f0.z, f0.w, f1.x, f1.y, f1.z, f1.w};
      bf16x8 ah, am;
#pragma unroll
      for (int j = 0; j < 8; ++j) {
        BF2 w = split2(fa[j]);
        ah[j] = w.h; am[j] = w.m;
      }
      const unsigned short* pb = pk + (size_t)s * 4096 + (size_t)lane * 8;
#pragma unroll
      for (int t = 0; t < 8; ++t) {
        bf16x8 bh = *(const bf16x8*)(pb + (size_t)t * 512);
        bf16x8 bm = *(const bf16x8*)(pb + (size_t)t * 512 + 16384);
        MFMA3(ah, am, bh, bm, acc[t]);
      }
    }
  }

  // bias
#pragma unroll
  for (int t = 0; t < 8; ++t) {
    float bv = blv[t * 16 + cg];
#pragma unroll
    for (int j = 0; j < 4; ++j) acc[t][j] += bv;
  }
  // l2norm + store/accumulate
  float ss[4];
#pragma unroll
  for (int j = 0; j < 4; ++j) {
    float s = 0.f;
#pragma unroll
    for (int t = 0; t < 8; ++t) s += acc[t][j] * acc[t][j];
    s += __shfl_xor(s, 1); s += __shfl_xor(s, 2);
    s += __shfl_xor(s, 4); s += __shfl_xor(s, 8);
    ss[j] = 1.0f / fmaxf(sqrtf(s), 1e-12f);
  }
#pragma unroll
  for (int j = 0; j < 4; ++j) {
    int r = row0 + qg * 4 + j;
    if (r < n_dst) {
      float* p = outp + (size_t)r * 128 + cg;
      if (first) {
#pragma unroll
        for (int t = 0; t < 8; ++t) p[t * 16] = acc[t][j] * ss[j];
      } else {
#pragma unroll
        for (int t = 0; t < 8; ++t) {
          float v = p[t * 16] + acc[t][j] * ss[j];
          if (relu_out) v = fmaxf(v, 0.f);
          p[t * 16] = v;
        }
      }
    }
  }
}

// ---------- head GEMM1 with fused LayerNorm: out = relu(LN(A)@pw1 + pb1) ----------
// 6-term split (output accuracy). Row stats reduced across the 4 qg lanes.
__global__ __launch_bounds__(256) void k_gemm1_ln(
    const float* __restrict__ A, const unsigned short* __restrict__ pk,
    const float* __restrict__ lng, const float* __restrict__ lnb,
    const float* __restrict__ bias, float* __restrict__ outp, int n) {
  int lane = threadIdx.x & 63, wave = threadIdx.x >> 6;
  int row0 = blockIdx.x * 64 + wave * 16;
  int cg = lane & 15, qg = lane >> 4;
  int ar = min(row0 + cg, n - 1);
  int kb = qg * 8;

  float va[4][8];
  float s1 = 0.f, s2 = 0.f;
#pragma unroll
  for (int s = 0; s < 4; ++s) {
    const float* ap = A + (size_t)ar * 128 + s * 32 + kb;
    float4 f0 = *(const float4*)ap;
    float4 f1 = *(const float4*)(ap + 4);
    va[s][0] = f0.x; va[s][1] = f0.y; va[s][2] = f0.z; va[s][3] = f0.w;
    va[s][4] = f1.x; va[s][5] = f1.y; va[s][6] = f1.z; va[s][7] = f1.w;
#pragma unroll
    for (int j = 0; j < 8; ++j) { s1 += va[s][j]; s2 += va[s][j] * va[s][j]; }
  }
  s1 += __shfl_xor(s1, 16); s1 += __shfl_xor(s1, 32);
  s2 += __shfl_xor(s2, 16); s2 += __shfl_xor(s2, 32);
  float mu = s1 * 0.0078125f;
  float rs = rsqrtf(s2 * 0.0078125f - mu * mu + 1e-5f);

  f32x4 acc[8];
#pragma unroll
  for (int t = 0; t < 8; ++t) acc[t] = (f32x4){0.f, 0.f, 0.f, 0.f};
#pragma unroll
  for (int s = 0; s < 4; ++s) {
    bf16x8 ah, am, al;
#pragma unroll
    for (int j = 0; j < 8; ++j) {
      int c = s * 32 + kb + j;
      float f = (va[s][j] - mu) * rs * lng[c] + lnb[c];
      BF3 w = split3(f);
      ah[j] = w.h; am[j] = w.m; al[j] = w.l;
    }
    const unsigned short* pb = pk + (size_t)s * 4096 + (size_t)lane * 8;
#pragma unroll
    for (int t = 0; t < 8; ++t) {
      bf16x8 bh  = *(const bf16x8*)(pb + (size_t)t * 512);
      bf16x8 bm  = *(const bf16x8*)(pb + (size_t)t * 512 + 16384);
      bf16x8 blo = *(const bf16x8*)(pb + (size_t)t * 512 + 32768);
      MFMA6(ah, am, al, bh, bm, blo, acc[t]);
    }
  }

#pragma unroll
  for (int t = 0; t < 8; ++t) {
    float bv = bias[t * 16 + cg];
#pragma unroll
    for (int j = 0; j < 4; ++j) {
      int r = row0 + qg * 4 + j;
      if (r < n) outp[(size_t)r * 128 + t * 16 + cg] = fmaxf(acc[t][j] + bv, 0.f);
    }
  }
}

// ---------- head GEMM2: out = l2norm(A@pw2 + pb2) ----------
__global__ __launch_bounds__(256) void k_gemm2(
    const float* __restrict__ A, const unsigned short* __restrict__ pk,
    const float* __restrict__ bias, float* __restrict__ outp, int n) {
  int lane = threadIdx.x & 63, wave = threadIdx.x >> 6;
  int row0 = blockIdx.x * 64 + wave * 16;
  int cg = lane & 15, qg = lane >> 4;
  int ar = min(row0 + cg, n - 1);
  int kb = qg * 8;

  f32x4 acc[8];
#pragma unroll
  for (int t = 0; t < 8; ++t) acc[t] = (f32x4){0.f, 0.f, 0.f, 0.f};
#pragma unroll
  for (int s = 0; s < 4; ++s) {
    const float* ap = A + (size_t)ar * 128 + s * 32 + kb;
    float4 f0 = *(const float4*)ap;
    float4 f1 = *(const float4*)(ap + 4);
    float fa[8] = {f0.x, f0.y, f0.z, f0.w, f1.x, f1.y, f1.z, f1.w};
    bf16x8 ah, am, al;
#pragma unroll
    for (int j = 0; j < 8; ++j) {
      BF3 w = split3(fa[j]);
      ah[j] = w.h; am[j] = w.m; al[j] = w.l;
    }
    const unsigned short* pb = pk + (size_t)s * 4096 + (size_t)lane * 8;
#pragma unroll
    for (int t = 0; t < 8; ++t) {
      bf16x8 bh  = *(const bf16x8*)(pb + (size_t)t * 512);
      bf16x8 bm  = *(const bf16x8*)(pb + (size_t)t * 512 + 16384);
      bf16x8 blo = *(const bf16x8*)(pb + (size_t)t * 512 + 32768);
      MFMA6(ah, am, al, bh, bm, blo, acc[t]);
    }
  }

#pragma unroll
  for (int t = 0; t < 8; ++t) {
    float bv = bias[t * 16 + cg];
#pragma unroll
    for (int j = 0; j < 4; ++j) acc[t][j] += bv;
  }
  float ss[4];
#pragma unroll
  for (int j = 0; j < 4; ++j) {
    float s = 0.f;
#pragma unroll
    for (int t = 0; t < 8; ++t) s += acc[t][j] * acc[t][j];
    s += __shfl_xor(s, 1); s += __shfl_xor(s, 2);
    s += __shfl_xor(s, 4); s += __shfl_xor(s, 8);
    ss[j] = 1.0f / fmaxf(sqrtf(s), 1e-12f);
  }
#pragma unroll
  for (int j = 0; j < 4; ++j) {
    int r = row0 + qg * 4 + j;
    if (r < n) {
      float* p = outp + (size_t)r * 128 + cg;
#pragma unroll
      for (int t = 0; t < 8; ++t) p[t * 16] = acc[t][j] * ss[j];
    }
  }
}

// ---------------------------------------------------------------------------
extern "C" void kernel_launch(void* const* d_in, const int* in_sizes, int n_in,
                              void* d_out, int out_size, void* d_ws, size_t ws_size,
                              hipStream_t stream) {
  const int* nid[3] = {(const int*)d_in[0], (const int*)d_in[1], (const int*)d_in[2]};
  const int* eg[6];
  for (int r = 0; r < 6; ++r) eg[r] = (const int*)d_in[3 + r];
  const float* emb[3] = {(const float*)d_in[9], (const float*)d_in[10], (const float*)d_in[11]};
  const float* Wl  = (const float*)d_in[12];
  const float* bl  = (const float*)d_in[13];
  const float* Wr  = (const float*)d_in[14];
  const float* lng = (const float*)d_in[15];
  const float* lnb = (const float*)d_in[16];
  const float* pw1 = (const float*)d_in[17];
  const float* pb1 = (const float*)d_in[18];
  const float* pw2 = (const float*)d_in[19];
  const float* pb2 = (const float*)d_in[20];

  static const int TOFF[3] = {0, NPF, NPF + NAR};
  static const int TN[3]   = {NPF, NAR, NSO};
  struct RelI { int st, dt, first; };
  static const RelI R[6] = {
    {1, 0, 1},   // artist -> performance
    {0, 2, 1},   // performance -> song
    {1, 2, 0},   // artist -> song
    {0, 1, 1},   // performance -> artist
    {2, 0, 0},   // song -> performance
    {2, 1, 0},   // song -> artist
  };
  static const int cnt_off[6] = {0, 200000, 250000, 300000, 330000, 530000};

  // workspace layout (~160 MB)
  float* cur = (float*)d_ws;                          // 280000*128 f32 (features + head scratch)
  int* col   = (int*)(cur + (size_t)280000 * 128);    // ETOT
  int* rp    = col + ETOT;                            // NDTOT+1
  int* cnt   = rp + NDTOT + 1;                        // NDTOT (counts, then fill cursors)
  int* part  = cnt + NDTOT;                           // 256
  size_t pk_off = ((size_t)((char*)(part + 256) - (char*)d_ws) + 255) & ~(size_t)255;
  unsigned short* pkw = (unsigned short*)((char*)d_ws + pk_off);  // 42*49152 ushorts = 4.03 MB
  float* dout = (float*)d_out;

  // pack all weights (42 matrices) into MFMA fragment order, bf16 hi/mid/lo
  k_packW<<<dim3(336), dim3(256), 0, stream>>>(Wl, Wr, pw1, pw2, pkw);

  // x0 = emb[nid] (all types, one kernel)
  k_gather_all<<<dim3((280000 * 32 + 255) / 256), dim3(256), 0, stream>>>(
      nid[0], nid[1], nid[2],
      (const float4*)emb[0], (const float4*)emb[1], (const float4*)emb[2],
      (float4*)cur);

  // concatenated CSR build (count -> scan (zeroes cnt) -> fill)
  hipMemsetAsync(cnt, 0, (size_t)NDTOT * 4, stream);
  k_count_all<<<dim3((ETOT + 255) / 256), dim3(256), 0, stream>>>(
      eg[0], eg[1], eg[2], eg[3], eg[4], eg[5], cnt);
  k_scan_block<<<dim3(SCAN_NB), dim3(256), 0, stream>>>(cnt, NDTOT, part);
  k_scan_top<<<dim3(1), dim3(256), 0, stream>>>(part, SCAN_NB);
  k_scan_final<<<dim3(SCAN_NB), dim3(256), 0, stream>>>(cnt, NDTOT, part, rp, ETOT);
  k_fill_all<<<dim3((ETOT + 255) / 256), dim3(256), 0, stream>>>(
      eg[0], eg[1], eg[2], eg[3], eg[4], eg[5], rp, cnt, col);

  // GNN layers; ping-pong cur <-> d_out (layer0: cur->dout, 1: dout->cur, 2: cur->dout)
  for (int layer = 0; layer < 3; ++layer) {
    float* xin  = (layer == 1) ? dout : cur;
    float* xout = (layer == 1) ? cur  : dout;
    int relu_o = (layer < 2) ? 1 : 0;
    for (int r = 0; r < 6; ++r) {
      int nd = TN[R[r].dt];
      int m = layer * 6 + r;
      const unsigned short* pkl = pkw + (size_t)m * PKSTRIDE;
      const unsigned short* pkr = pkw + (size_t)(18 + m) * PKSTRIDE;
      const float* bb = bl + ((size_t)layer * 6 + r) * 128;
      k_sage_fused<<<dim3((nd + 63) / 64), dim3(256), 0, stream>>>(
          rp + cnt_off[r], col,
          xin + (size_t)TOFF[R[r].st] * 128, xin + (size_t)TOFF[R[r].dt] * 128,
          pkl, pkr, bb,
          xout + (size_t)TOFF[R[r].dt] * 128, nd, R[r].first, relu_o);
    }
  }

  // head per type: GEMM1(+fused LN, relu) dout->cur, GEMM2(+l2norm) cur->dout.
  // cur (layer-1 features) is dead at this point — reused as scratch.
  for (int t = 0; t < 3; ++t) {
    int n = TN[t];
    const unsigned short* pk1 = pkw + (size_t)(36 + t) * PKSTRIDE;
    const unsigned short* pk2 = pkw + (size_t)(39 + t) * PKSTRIDE;
    k_gemm1_ln<<<dim3((n + 63) / 64), dim3(256), 0, stream>>>(
        dout + (size_t)TOFF[t] * 128, pk1, lng + t * 128, lnb + t * 128,
        pb1 + t * 128, cur, n);
    k_gemm2<<<dim3((n + 63) / 64), dim3(256), 0, stream>>>(
        cur, pk2, pb2 + t * 128, dout + (size_t)TOFF[t] * 128, n);
  }

  (void)in_sizes; (void)n_in; (void)out_size; (void)ws_size;
}

// Round 9
// 2088.313 us; speedup vs baseline: 1.6014x; 1.0032x over previous
//
#include <hip/hip_runtime.h>
#include <math.h>

// ---------------------------------------------------------------------------
// Heterogeneous GraphSAGE (3 types, 6 relations, D=128, L=3) + MLP head.
// Round 6: (1) phase-A gather rewritten slot-major w/ 16-lane groups (16x
// memory-level parallelism); (2) sage GEMMs drop to 3-term split-bf16 (head
// stays 6-term); (3) head LN fused into GEMM1; (4) CSR build consolidated
// into one concatenated count/scan/fill.
//
// Node row layout: [performance 0..200000) [artist ..230000) [song ..280000)
// ---------------------------------------------------------------------------

#define NPF 200000
#define NAR 30000
#define NSO 50000
#define NDTOT 560000     // sum of per-relation dst-node counts
#define ETOT  1900000    // total edges
#define VPT 12
#define SCAN_CHUNK (256 * VPT)   // 3072
#define SCAN_NB 183              // ceil(560000/3072)

typedef __attribute__((ext_vector_type(8))) short bf16x8;
typedef __attribute__((ext_vector_type(4))) float f32x4;

__device__ __forceinline__ unsigned short f2bf(float f) {
  union { float f; unsigned u; } v; v.f = f;
  unsigned u = v.u;
  u += 0x7FFFu + ((u >> 16) & 1u);
  return (unsigned short)(u >> 16);
}
__device__ __forceinline__ float bf2f(unsigned short h) {
  union { unsigned u; float f; } v; v.u = ((unsigned)h) << 16;
  return v.f;
}

struct BF3 { short h, m, l; };
__device__ __forceinline__ BF3 split3(float f) {
  BF3 r;
  unsigned short hh = f2bf(f);
  float r1 = f - bf2f(hh);
  unsigned short mm = f2bf(r1);
  float r2 = r1 - bf2f(mm);
  r.h = (short)hh; r.m = (short)mm; r.l = (short)f2bf(r2);
  return r;
}
struct BF2 { short h, m; };
__device__ __forceinline__ BF2 split2(float f) {
  BF2 r;
  unsigned short hh = f2bf(f);
  r.h = (short)hh;
  r.m = (short)f2bf(f - bf2f(hh));
  return r;
}

// 6-product (head) and 3-product (sage) split-bf16 MFMA accumulate
#define MFMA6(ah, am, al, bh, bm, blo, acc)                                     \
  acc = __builtin_amdgcn_mfma_f32_16x16x32_bf16(ah, bh, acc, 0, 0, 0);          \
  acc = __builtin_amdgcn_mfma_f32_16x16x32_bf16(am, bh, acc, 0, 0, 0);          \
  acc = __builtin_amdgcn_mfma_f32_16x16x32_bf16(ah, bm, acc, 0, 0, 0);          \
  acc = __builtin_amdgcn_mfma_f32_16x16x32_bf16(al, bh, acc, 0, 0, 0);          \
  acc = __builtin_amdgcn_mfma_f32_16x16x32_bf16(am, bm, acc, 0, 0, 0);          \
  acc = __builtin_amdgcn_mfma_f32_16x16x32_bf16(ah, blo, acc, 0, 0, 0);
#define MFMA3(ah, am, bh, bm, acc)                                              \
  acc = __builtin_amdgcn_mfma_f32_16x16x32_bf16(ah, bh, acc, 0, 0, 0);          \
  acc = __builtin_amdgcn_mfma_f32_16x16x32_bf16(am, bh, acc, 0, 0, 0);          \
  acc = __builtin_amdgcn_mfma_f32_16x16x32_bf16(ah, bm, acc, 0, 0, 0);

// ---------- fused gather x0 = emb[nid] over all 3 types ----------
__global__ void k_gather_all(const int* __restrict__ nidP, const int* __restrict__ nidA,
                             const int* __restrict__ nidS,
                             const float4* __restrict__ embP, const float4* __restrict__ embA,
                             const float4* __restrict__ embS, float4* __restrict__ dst) {
  int i = blockIdx.x * blockDim.x + threadIdx.x;
  if (i >= 280000 * 32) return;
  int r = i >> 5, c = i & 31;
  const int* nid; const float4* emb; int lr;
  if (r < NPF)            { nid = nidP; emb = embP; lr = r; }
  else if (r < NPF + NAR) { nid = nidA; emb = embA; lr = r - NPF; }
  else                    { nid = nidS; emb = embS; lr = r - NPF - NAR; }
  dst[(size_t)r * 32 + c] = emb[(size_t)nid[lr] * 32 + c];
}

// ---------- concatenated CSR build over all 6 relations ----------
// relation edge ranges: [0,400k) [400k,800k) [800k,950k) [950k,1.35M) [1.35M,1.75M) [1.75M,1.9M)
// cnt offsets (dst nodes): {0, 200000, 250000, 300000, 330000, 530000}
__device__ __forceinline__ void edge_decode(int i,
    const int* e0, const int* e1, const int* e2, const int* e3, const int* e4, const int* e5,
    const int** eg, int* lo, int* E, int* co) {
  if (i < 400000)       { *eg = e0; *lo = i;           *E = 400000; *co = 0; }
  else if (i < 800000)  { *eg = e1; *lo = i - 400000;  *E = 400000; *co = 200000; }
  else if (i < 950000)  { *eg = e2; *lo = i - 800000;  *E = 150000; *co = 250000; }
  else if (i < 1350000) { *eg = e3; *lo = i - 950000;  *E = 400000; *co = 300000; }
  else if (i < 1750000) { *eg = e4; *lo = i - 1350000; *E = 400000; *co = 330000; }
  else                  { *eg = e5; *lo = i - 1750000; *E = 150000; *co = 530000; }
}

__global__ void k_count_all(const int* e0, const int* e1, const int* e2,
                            const int* e3, const int* e4, const int* e5,
                            int* __restrict__ cnt) {
  int i = blockIdx.x * blockDim.x + threadIdx.x;
  if (i >= ETOT) return;
  const int* eg; int lo, E, co;
  edge_decode(i, e0, e1, e2, e3, e4, e5, &eg, &lo, &E, &co);
  atomicAdd(&cnt[co + eg[E + lo]], 1);
}

__global__ void k_scan_block(const int* __restrict__ cnt, int n, int* __restrict__ part) {
  __shared__ int sd[256];
  int t = threadIdx.x;
  int base = blockIdx.x * SCAN_CHUNK + t * VPT;
  int s = 0;
#pragma unroll
  for (int i = 0; i < VPT; ++i) { int idx = base + i; if (idx < n) s += cnt[idx]; }
  sd[t] = s; __syncthreads();
  for (int off = 128; off > 0; off >>= 1) { if (t < off) sd[t] += sd[t + off]; __syncthreads(); }
  if (t == 0) part[blockIdx.x] = sd[0];
}

__global__ void k_scan_top(int* part, int nb) {
  __shared__ int sd[256];
  int t = threadIdx.x;
  int v = (t < nb) ? part[t] : 0;
  sd[t] = v; __syncthreads();
  for (int off = 1; off < 256; off <<= 1) {
    int add = (t >= off) ? sd[t - off] : 0;
    __syncthreads();
    sd[t] += add;
    __syncthreads();
  }
  if (t < nb) part[t] = sd[t] - v;  // exclusive
}

// also zeroes cnt so it can be reused as the fill cursor array
__global__ void k_scan_final(int* __restrict__ cnt, int n, const int* __restrict__ part,
                             int* __restrict__ rp, int E) {
  __shared__ int sd[256];
  int t = threadIdx.x;
  int base = blockIdx.x * SCAN_CHUNK + t * VPT;
  int v[VPT]; int s = 0;
#pragma unroll
  for (int i = 0; i < VPT; ++i) { int idx = base + i; v[i] = (idx < n) ? cnt[idx] : 0; s += v[i]; }
  sd[t] = s; __syncthreads();
  for (int off = 1; off < 256; off <<= 1) {
    int add = (t >= off) ? sd[t - off] : 0;
    __syncthreads();
    sd[t] += add;
    __syncthreads();
  }
  int run = part[blockIdx.x] + sd[t] - s;
#pragma unroll
  for (int i = 0; i < VPT; ++i) {
    int idx = base + i;
    if (idx < n) { rp[idx] = run; cnt[idx] = 0; }
    run += v[i];
  }
  if (blockIdx.x == 0 && t == 0) rp[n] = E;
}

__global__ void k_fill_all(const int* e0, const int* e1, const int* e2,
                           const int* e3, const int* e4, const int* e5,
                           const int* __restrict__ rp, int* __restrict__ cur,
                           int* __restrict__ col) {
  int i = blockIdx.x * blockDim.x + threadIdx.x;
  if (i >= ETOT) return;
  const int* eg; int lo, E, co;
  edge_decode(i, e0, e1, e2, e3, e4, e5, &eg, &lo, &E, &co);
  int d = co + eg[E + lo];
  int p = atomicAdd(&cur[d], 1);
  col[rp[d] + p] = eg[lo];
}

// ---------- pack weights into MFMA B-fragment order, bf16 hi/mid/lo ----------
// matrix m: [0,18)=Wl[layer*6+r], [18,36)=Wr, [36,39)=pw1[type], [39,42)=pw2[type]
#define PKSTRIDE 49152
__global__ void k_packW(const float* __restrict__ Wl, const float* __restrict__ Wr,
                        const float* __restrict__ pw1, const float* __restrict__ pw2,
                        unsigned short* __restrict__ pk) {
  int gid = blockIdx.x * blockDim.x + threadIdx.x;
  if (gid >= 42 * 4 * 8 * 64) return;
  int lane = gid & 63;
  int t = (gid >> 6) & 7;
  int s = (gid >> 9) & 3;
  int m = gid >> 11;
  const float* src;
  if (m < 18) src = Wl + (size_t)m * 16384;
  else if (m < 36) src = Wr + (size_t)(m - 18) * 16384;
  else if (m < 39) src = pw1 + (size_t)(m - 36) * 16384;
  else src = pw2 + (size_t)(m - 39) * 16384;
  int n = t * 16 + (lane & 15);
  int k0 = s * 32 + (lane >> 4) * 8;
  unsigned short* hi = pk + (size_t)m * PKSTRIDE + ((size_t)(s * 8 + t) * 64 + lane) * 8;
  unsigned short* mid = hi + 16384;
  unsigned short* lo = hi + 32768;
#pragma unroll
  for (int j = 0; j < 8; ++j) {
    float f = src[(size_t)(k0 + j) * 128 + n];
    BF3 w = split3(f);
    hi[j] = (unsigned short)w.h;
    mid[j] = (unsigned short)w.m;
    lo[j] = (unsigned short)w.l;
  }
}

// ---------- fused agg + SAGE: out = l2norm(mean(x_src)@Wl + bl + x_dst@Wr) ----------
// Phase A (new): 16-lane groups, 4 rows/group, slot-major neighbor loop ->
// up to 16 rows x 512B gathers in flight per wave. Phase B: 3-term MFMA.
__global__ __launch_bounds__(256) void k_sage_fused(
    const int* __restrict__ rp, const int* __restrict__ col,
    const float* __restrict__ xsrc, const float* __restrict__ xdst,
    const unsigned short* __restrict__ pkl, const unsigned short* __restrict__ pkr,
    const float* __restrict__ blv, float* __restrict__ outp,
    int n_dst, int first, int relu_out) {
  __shared__ float Ms[64][132];
  int lane = threadIdx.x & 63;
  int wave = threadIdx.x >> 6;
  int row0b = blockIdx.x * 64;

  // ---- phase A: segment mean into Ms ----
  {
    int g = lane >> 4, li = lane & 15;
    int c0 = li * 8;
    int bb[4], ne[4];
    int maxd = 0;
#pragma unroll
    for (int i = 0; i < 4; ++i) {
      int d = row0b + wave * 16 + g * 4 + i;
      int b = 0, e = 0;
      if (d < n_dst) { b = rp[d]; e = rp[d + 1]; }
      bb[i] = b; ne[i] = e - b;
      maxd = max(maxd, e - b);
    }
    f32x4 a0[4], a1[4];
#pragma unroll
    for (int i = 0; i < 4; ++i) { a0[i] = (f32x4){0.f,0.f,0.f,0.f}; a1[i] = (f32x4){0.f,0.f,0.f,0.f}; }
    for (int k = 0; k < maxd; ++k) {
#pragma unroll
      for (int i = 0; i < 4; ++i) {
        if (k < ne[i]) {
          int s = col[bb[i] + k];
          const float* sp = xsrc + (size_t)s * 128 + c0;
          float4 v0 = *(const float4*)sp;
          float4 v1 = *(const float4*)(sp + 4);
          a0[i][0] += v0.x; a0[i][1] += v0.y; a0[i][2] += v0.z; a0[i][3] += v0.w;
          a1[i][0] += v1.x; a1[i][1] += v1.y; a1[i][2] += v1.z; a1[i][3] += v1.w;
        }
      }
    }
#pragma unroll
    for (int i = 0; i < 4; ++i) {
      float inv = (ne[i] > 0) ? 1.0f / (float)ne[i] : 0.0f;
      int lr = wave * 16 + g * 4 + i;
      *(float4*)&Ms[lr][c0]     = make_float4(a0[i][0]*inv, a0[i][1]*inv, a0[i][2]*inv, a0[i][3]*inv);
      *(float4*)&Ms[lr][c0 + 4] = make_float4(a1[i][0]*inv, a1[i][1]*inv, a1[i][2]*inv, a1[i][3]*inv);
    }
  }
  __syncthreads();

  // ---- phase B: 3-term split-bf16 MFMA ----
  int row0 = row0b + wave * 16;
  int cg = lane & 15, qg = lane >> 4;
  int ar = min(row0 + cg, n_dst - 1);
  int lar = wave * 16 + cg;
  int kb = qg * 8;

  f32x4 acc[8];
#pragma unroll
  for (int t = 0; t < 8; ++t) acc[t] = (f32x4){0.f, 0.f, 0.f, 0.f};

#pragma unroll
  for (int sm = 0; sm < 2; ++sm) {
    const unsigned short* pk = sm ? pkr : pkl;
#pragma unroll
    for (int s = 0; s < 4; ++s) {
      const float* ap = sm ? (xdst + (size_t)ar * 128 + s * 32 + kb)
                           : (&Ms[lar][s * 32 + kb]);
      float4 f0 = *(const float4*)ap;
      float4 f1 = *(const float4*)(ap + 4);
      float fa[8] = {f0.x, f0.y, f0.z, f0.w, f1.x, f1.y, f1.z, f1.w};
      bf16x8 ah, am;
#pragma unroll
      for (int j = 0; j < 8; ++j) {
        BF2 w = split2(fa[j]);
        ah[j] = w.h; am[j] = w.m;
      }
      const unsigned short* pb = pk + (size_t)s * 4096 + (size_t)lane * 8;
#pragma unroll
      for (int t = 0; t < 8; ++t) {
        bf16x8 bh = *(const bf16x8*)(pb + (size_t)t * 512);
        bf16x8 bm = *(const bf16x8*)(pb + (size_t)t * 512 + 16384);
        MFMA3(ah, am, bh, bm, acc[t]);
      }
    }
  }

  // bias
#pragma unroll
  for (int t = 0; t < 8; ++t) {
    float bv = blv[t * 16 + cg];
#pragma unroll
    for (int j = 0; j < 4; ++j) acc[t][j] += bv;
  }
  // l2norm + store/accumulate
  float ss[4];
#pragma unroll
  for (int j = 0; j < 4; ++j) {
    float s = 0.f;
#pragma unroll
    for (int t = 0; t < 8; ++t) s += acc[t][j] * acc[t][j];
    s += __shfl_xor(s, 1); s += __shfl_xor(s, 2);
    s += __shfl_xor(s, 4); s += __shfl_xor(s, 8);
    ss[j] = 1.0f / fmaxf(sqrtf(s), 1e-12f);
  }
#pragma unroll
  for (int j = 0; j < 4; ++j) {
    int r = row0 + qg * 4 + j;
    if (r < n_dst) {
      float* p = outp + (size_t)r * 128 + cg;
      if (first) {
#pragma unroll
        for (int t = 0; t < 8; ++t) p[t * 16] = acc[t][j] * ss[j];
      } else {
#pragma unroll
        for (int t = 0; t < 8; ++t) {
          float v = p[t * 16] + acc[t][j] * ss[j];
          if (relu_out) v = fmaxf(v, 0.f);
          p[t * 16] = v;
        }
      }
    }
  }
}

// ---------- head GEMM1 with fused LayerNorm: out = relu(LN(A)@pw1 + pb1) ----------
// 6-term split (output accuracy). Row stats reduced across the 4 qg lanes.
__global__ __launch_bounds__(256) void k_gemm1_ln(
    const float* __restrict__ A, const unsigned short* __restrict__ pk,
    const float* __restrict__ lng, const float* __restrict__ lnb,
    const float* __restrict__ bias, float* __restrict__ outp, int n) {
  int lane = threadIdx.x & 63, wave = threadIdx.x >> 6;
  int row0 = blockIdx.x * 64 + wave * 16;
  int cg = lane & 15, qg = lane >> 4;
  int ar = min(row0 + cg, n - 1);
  int kb = qg * 8;

  float va[4][8];
  float s1 = 0.f, s2 = 0.f;
#pragma unroll
  for (int s = 0; s < 4; ++s) {
    const float* ap = A + (size_t)ar * 128 + s * 32 + kb;
    float4 f0 = *(const float4*)ap;
    float4 f1 = *(const float4*)(ap + 4);
    va[s][0] = f0.x; va[s][1] = f0.y; va[s][2] = f0.z; va[s][3] = f0.w;
    va[s][4] = f1.x; va[s][5] = f1.y; va[s][6] = f1.z; va[s][7] = f1.w;
#pragma unroll
    for (int j = 0; j < 8; ++j) { s1 += va[s][j]; s2 += va[s][j] * va[s][j]; }
  }
  s1 += __shfl_xor(s1, 16); s1 += __shfl_xor(s1, 32);
  s2 += __shfl_xor(s2, 16); s2 += __shfl_xor(s2, 32);
  float mu = s1 * 0.0078125f;
  float rs = rsqrtf(s2 * 0.0078125f - mu * mu + 1e-5f);

  f32x4 acc[8];
#pragma unroll
  for (int t = 0; t < 8; ++t) acc[t] = (f32x4){0.f, 0.f, 0.f, 0.f};
#pragma unroll
  for (int s = 0; s < 4; ++s) {
    bf16x8 ah, am, al;
#pragma unroll
    for (int j = 0; j < 8; ++j) {
      int c = s * 32 + kb + j;
      float f = (va[s][j] - mu) * rs * lng[c] + lnb[c];
      BF3 w = split3(f);
      ah[j] = w.h; am[j] = w.m; al[j] = w.l;
    }
    const unsigned short* pb = pk + (size_t)s * 4096 + (size_t)lane * 8;
#pragma unroll
    for (int t = 0; t < 8; ++t) {
      bf16x8 bh  = *(const bf16x8*)(pb + (size_t)t * 512);
      bf16x8 bm  = *(const bf16x8*)(pb + (size_t)t * 512 + 16384);
      bf16x8 blo = *(const bf16x8*)(pb + (size_t)t * 512 + 32768);
      MFMA6(ah, am, al, bh, bm, blo, acc[t]);
    }
  }

#pragma unroll
  for (int t = 0; t < 8; ++t) {
    float bv = bias[t * 16 + cg];
#pragma unroll
    for (int j = 0; j < 4; ++j) {
      int r = row0 + qg * 4 + j;
      if (r < n) outp[(size_t)r * 128 + t * 16 + cg] = fmaxf(acc[t][j] + bv, 0.f);
    }
  }
}

// ---------- head GEMM2: out = l2norm(A@pw2 + pb2) ----------
__global__ __launch_bounds__(256) void k_gemm2(
    const float* __restrict__ A, const unsigned short* __restrict__ pk,
    const float* __restrict__ bias, float* __restrict__ outp, int n) {
  int lane = threadIdx.x & 63, wave = threadIdx.x >> 6;
  int row0 = blockIdx.x * 64 + wave * 16;
  int cg = lane & 15, qg = lane >> 4;
  int ar = min(row0 + cg, n - 1);
  int kb = qg * 8;

  f32x4 acc[8];
#pragma unroll
  for (int t = 0; t < 8; ++t) acc[t] = (f32x4){0.f, 0.f, 0.f, 0.f};
#pragma unroll
  for (int s = 0; s < 4; ++s) {
    const float* ap = A + (size_t)ar * 128 + s * 32 + kb;
    float4 f0 = *(const float4*)ap;
    float4 f1 = *(const float4*)(ap + 4);
    float fa[8] = {f0.x, f0.y, f0.z, f0.w, f1.x, f1.y, f1.z, f1.w};
    bf16x8 ah, am, al;
#pragma unroll
    for (int j = 0; j < 8; ++j) {
      BF3 w = split3(fa[j]);
      ah[j] = w.h; am[j] = w.m; al[j] = w.l;
    }
    const unsigned short* pb = pk + (size_t)s * 4096 + (size_t)lane * 8;
#pragma unroll
    for (int t = 0; t < 8; ++t) {
      bf16x8 bh  = *(const bf16x8*)(pb + (size_t)t * 512);
      bf16x8 bm  = *(const bf16x8*)(pb + (size_t)t * 512 + 16384);
      bf16x8 blo = *(const bf16x8*)(pb + (size_t)t * 512 + 32768);
      MFMA6(ah, am, al, bh, bm, blo, acc[t]);
    }
  }

#pragma unroll
  for (int t = 0; t < 8; ++t) {
    float bv = bias[t * 16 + cg];
#pragma unroll
    for (int j = 0; j < 4; ++j) acc[t][j] += bv;
  }
  float ss[4];
#pragma unroll
  for (int j = 0; j < 4; ++j) {
    float s = 0.f;
#pragma unroll
    for (int t = 0; t < 8; ++t) s += acc[t][j] * acc[t][j];
    s += __shfl_xor(s, 1); s += __shfl_xor(s, 2);
    s += __shfl_xor(s, 4); s += __shfl_xor(s, 8);
    ss[j] = 1.0f / fmaxf(sqrtf(s), 1e-12f);
  }
#pragma unroll
  for (int j = 0; j < 4; ++j) {
    int r = row0 + qg * 4 + j;
    if (r < n) {
      float* p = outp + (size_t)r * 128 + cg;
#pragma unroll
      for (int t = 0; t < 8; ++t) p[t * 16] = acc[t][j] * ss[j];
    }
  }
}

// ---------------------------------------------------------------------------
extern "C" void kernel_launch(void* const* d_in, const int* in_sizes, int n_in,
                              void* d_out, int out_size, void* d_ws, size_t ws_size,
                              hipStream_t stream) {
  const int* nid[3] = {(const int*)d_in[0], (const int*)d_in[1], (const int*)d_in[2]};
  const int* eg[6];
  for (int r = 0; r < 6; ++r) eg[r] = (const int*)d_in[3 + r];
  const float* emb[3] = {(const float*)d_in[9], (const float*)d_in[10], (const float*)d_in[11]};
  const float* Wl  = (const float*)d_in[12];
  const float* bl  = (const float*)d_in[13];
  const float* Wr  = (const float*)d_in[14];
  const float* lng = (const float*)d_in[15];
  const float* lnb = (const float*)d_in[16];
  const float* pw1 = (const float*)d_in[17];
  const float* pb1 = (const float*)d_in[18];
  const float* pw2 = (const float*)d_in[19];
  const float* pb2 = (const float*)d_in[20];

  static const int TOFF[3] = {0, NPF, NPF + NAR};
  static const int TN[3]   = {NPF, NAR, NSO};
  struct RelI { int st, dt, first; };
  static const RelI R[6] = {
    {1, 0, 1},   // artist -> performance
    {0, 2, 1},   // performance -> song
    {1, 2, 0},   // artist -> song
    {0, 1, 1},   // performance -> artist
    {2, 0, 0},   // song -> performance
    {2, 1, 0},   // song -> artist
  };
  static const int cnt_off[6] = {0, 200000, 250000, 300000, 330000, 530000};

  // workspace layout (~160 MB)
  float* cur = (float*)d_ws;                          // 280000*128 f32 (features + head scratch)
  int* col   = (int*)(cur + (size_t)280000 * 128);    // ETOT
  int* rp    = col + ETOT;                            // NDTOT+1
  int* cnt   = rp + NDTOT + 1;                        // NDTOT (counts, then fill cursors)
  int* part  = cnt + NDTOT;                           // 256
  size_t pk_off = ((size_t)((char*)(part + 256) - (char*)d_ws) + 255) & ~(size_t)255;
  unsigned short* pkw = (unsigned short*)((char*)d_ws + pk_off);  // 42*49152 ushorts = 4.03 MB
  float* dout = (float*)d_out;

  // pack all weights (42 matrices) into MFMA fragment order, bf16 hi/mid/lo
  k_packW<<<dim3(336), dim3(256), 0, stream>>>(Wl, Wr, pw1, pw2, pkw);

  // x0 = emb[nid] (all types, one kernel)
  k_gather_all<<<dim3((280000 * 32 + 255) / 256), dim3(256), 0, stream>>>(
      nid[0], nid[1], nid[2],
      (const float4*)emb[0], (const float4*)emb[1], (const float4*)emb[2],
      (float4*)cur);

  // concatenated CSR build (count -> scan (zeroes cnt) -> fill)
  hipMemsetAsync(cnt, 0, (size_t)NDTOT * 4, stream);
  k_count_all<<<dim3((ETOT + 255) / 256), dim3(256), 0, stream>>>(
      eg[0], eg[1], eg[2], eg[3], eg[4], eg[5], cnt);
  k_scan_block<<<dim3(SCAN_NB), dim3(256), 0, stream>>>(cnt, NDTOT, part);
  k_scan_top<<<dim3(1), dim3(256), 0, stream>>>(part, SCAN_NB);
  k_scan_final<<<dim3(SCAN_NB), dim3(256), 0, stream>>>(cnt, NDTOT, part, rp, ETOT);
  k_fill_all<<<dim3((ETOT + 255) / 256), dim3(256), 0, stream>>>(
      eg[0], eg[1], eg[2], eg[3], eg[4], eg[5], rp, cnt, col);

  // GNN layers; ping-pong cur <-> d_out (layer0: cur->dout, 1: dout->cur, 2: cur->dout)
  for (int layer = 0; layer < 3; ++layer) {
    float* xin  = (layer == 1) ? dout : cur;
    float* xout = (layer == 1) ? cur  : dout;
    int relu_o = (layer < 2) ? 1 : 0;
    for (int r = 0; r < 6; ++r) {
      int nd = TN[R[r].dt];
      int m = layer * 6 + r;
      const unsigned short* pkl = pkw + (size_t)m * PKSTRIDE;
      const unsigned short* pkr = pkw + (size_t)(18 + m) * PKSTRIDE;
      const float* bb = bl + ((size_t)layer * 6 + r) * 128;
      k_sage_fused<<<dim3((nd + 63) / 64), dim3(256), 0, stream>>>(
          rp + cnt_off[r], col,
          xin + (size_t)TOFF[R[r].st] * 128, xin + (size_t)TOFF[R[r].dt] * 128,
          pkl, pkr, bb,
          xout + (size_t)TOFF[R[r].dt] * 128, nd, R[r].first, relu_o);
    }
  }

  // head per type: GEMM1(+fused LN, relu) dout->cur, GEMM2(+l2norm) cur->dout.
  // cur (layer-1 features) is dead at this point — reused as scratch.
  for (int t = 0; t < 3; ++t) {
    int n = TN[t];
    const unsigned short* pk1 = pkw + (size_t)(36 + t) * PKSTRIDE;
    const unsigned short* pk2 = pkw + (size_t)(39 + t) * PKSTRIDE;
    k_gemm1_ln<<<dim3((n + 63) / 64), dim3(256), 0, stream>>>(
        dout + (size_t)TOFF[t] * 128, pk1, lng + t * 128, lnb + t * 128,
        pb1 + t * 128, cur, n);
    k_gemm2<<<dim3((n + 63) / 64), dim3(256), 0, stream>>>(
        cur, pk2, pb2 + t * 128, dout + (size_t)TOFF[t] * 128, n);
  }

  (void)in_sizes; (void)n_in; (void)out_size; (void)ws_size;
}